// Round 6
// baseline (953.161 us; speedup 1.0000x reference)
//
#include <hip/hip_runtime.h>
#include <hip/hip_cooperative_groups.h>
#include <math.h>

namespace cg = cooperative_groups;

#define G      1708
#define NH     5
#define NB     16
#define NC     34
#define JB     7            // j-chunks; G = 7*244 exactly
#define JCH    244
#define C4     61           // JCH/4
#define JSL    8            // j-slices (threads) per i-group
#define ITR    2            // i per thread
#define IPB    64           // i per block-item
#define IBLK   27           // ceil(G/IPB)
#define ITEMS  (IBLK*JB*NB) // 3024
#define LN_EPS 1e-6f
#define LOG2E  1.4426950408889634f

// monotone float<->uint key map for atomic min/max on floats
__device__ __forceinline__ unsigned enc(float f) {
    unsigned u = __float_as_uint(f);
    return (u & 0x80000000u) ? ~u : (u | 0x80000000u);
}
__device__ __forceinline__ float dec(unsigned k) {
    return (k & 0x80000000u) ? __uint_as_float(k ^ 0x80000000u)
                             : __uint_as_float(~k);
}

// ---------------------------------------------------------------------------
// One cooperative kernel for the whole net. Phases separated by grid.sync().
// Rank-1 score: s_ij = q_i*k_j => exact row max m_i = max(q_i*kmax, q_i*kmin)
// => partial softmax sums over j-chunks are directly addable (atomicAdd).
// ---------------------------------------------------------------------------
__global__ __launch_bounds__(256, 4) void fused(
    const float* __restrict__ x,
    const float* __restrict__ WQ1, const float* __restrict__ WK1,
    const float* __restrict__ WV1, const float* __restrict__ W01,
    const float* __restrict__ WQ2, const float* __restrict__ WK2,
    const float* __restrict__ WV2, const float* __restrict__ W02,
    const float* __restrict__ WQ3, const float* __restrict__ WK3,
    const float* __restrict__ WV3, const float* __restrict__ W03,
    const float* __restrict__ lna, const float* __restrict__ lnb,
    const float* __restrict__ fcw, const float* __restrict__ fcb,
    float* __restrict__ outp,
    float* __restrict__ abuf, float* __restrict__ hbuf,
    float* __restrict__ lgt, float* __restrict__ stats,
    unsigned* __restrict__ kmm, float* __restrict__ S1t,
    float* __restrict__ S2t)
{
    cg::grid_group gg = cg::this_grid();
    const int tid  = threadIdx.x, bid = blockIdx.x, nb = gridDim.x;
    const int gt   = bid * 256 + tid, T = nb * 256;
    const int lane = tid & 63;
    const int wid  = gt >> 6, NW = T >> 6;

    __shared__ float    kc[NH][JCH];
    __shared__ float    vc[NH][JCH];
    __shared__ float    sls[2][2];
    __shared__ unsigned lmx[2][NH], lmn[2][NH];

    const float* WQa[3] = {WQ1, WQ2, WQ3};
    const float* WKa[3] = {WK1, WK2, WK3};
    const float* WVa[3] = {WV1, WV2, WV3};
    const float* W0a[3] = {W01, W02, W03};

    // ---- phase 0: init totals / stats / kmm keys ----
    for (int z = gt; z < NB * NH * G; z += T) { S1t[z] = 0.f; S2t[z] = 0.f; }
    if (gt < 3 * NB * NH) { kmm[gt * 2] = 0u; kmm[gt * 2 + 1] = 0xFFFFFFFFu; }
    if (gt < 3 * NB * 2) stats[gt] = 0.f;
    gg.sync();

    // ---- phase 1: layer-1 k-table min/max (wave items) ----
    for (int it = wid; it < NB * NH * 27; it += NW) {
        int seg = it % 27, bh = it / 27, h = bh % NH, b = bh / NH;
        int j = seg * 64 + lane;
        bool v = j < G;
        float kl = v ? x[b * G + j] * WK1[h * G + j] * LOG2E : 0.f;
        float mx = v ? kl : -INFINITY, mn = v ? kl : INFINITY;
        for (int o = 1; o < 64; o <<= 1) {
            mx = fmaxf(mx, __shfl_xor(mx, o));
            mn = fminf(mn, __shfl_xor(mn, o));
        }
        if (lane == 0) {
            atomicMax(&kmm[(b * NH + h) * 2], enc(mx));
            atomicMin(&kmm[(b * NH + h) * 2 + 1], enc(mn));
        }
    }
    gg.sync();

    for (int l = 0; l < 3; ++l) {
        const float* hin = (l == 0) ? x : hbuf;
        const float* WQ = WQa[l];
        const float* WK = WKa[l];
        const float* WV = WVa[l];
        const float* W0 = W0a[l];
        const unsigned* km = kmm + l * NB * NH * 2;
        float* st = stats + l * NB * 2;

        // ---- partial phase: items (iblk, jb, b) ----
        for (int item = bid; item < ITEMS; item += nb) {
            __syncthreads();                       // protect LDS reuse
            int b   = item / (IBLK * JB);
            int rem = item - b * (IBLK * JB);
            int jb  = rem / IBLK;
            int ibk = rem - jb * IBLK;
            int jg  = jb * JCH;
            for (int s = tid; s < NH * JCH; s += 256) {
                int h = s / JCH, jj = s - h * JCH;
                float xv = hin[b * G + jg + jj];
                kc[h][jj] = xv * WK[h * G + jg + jj] * LOG2E;
                vc[h][jj] = xv * WV[h * G + jg + jj];
            }
            __syncthreads();

            int ig = tid >> 3, sl = tid & 7;
            int i0 = ibk * IPB + ig * ITR;
            bool valid = i0 < G;                   // i0 even, G even
            int is = valid ? i0 : 0;
            float2 xi2 = *reinterpret_cast<const float2*>(hin + b * G + is);

            float q0[NH], q1[NH], m0[NH], m1[NH];
            float S10[NH], S11[NH], S20[NH], S21[NH];
#pragma unroll
            for (int h = 0; h < NH; ++h) {
                float kx = dec(km[(b * NH + h) * 2]);
                float kn = dec(km[(b * NH + h) * 2 + 1]);
                float2 wq = *reinterpret_cast<const float2*>(WQ + h * G + is);
                q0[h] = xi2.x * wq.x;
                q1[h] = xi2.y * wq.y;
                m0[h] = fmaxf(q0[h] * kx, q0[h] * kn);
                m1[h] = fmaxf(q1[h] * kx, q1[h] * kn);
                S10[h] = 0.f; S11[h] = 0.f; S20[h] = 0.f; S21[h] = 0.f;
            }

            for (int c = sl; c < C4; c += JSL) {
#pragma unroll
                for (int h = 0; h < NH; ++h) {
                    float4 kk = reinterpret_cast<const float4*>(kc[h])[c];
                    float4 vq = reinterpret_cast<const float4*>(vc[h])[c];
                    float a0 = __builtin_amdgcn_exp2f(fmaf(q0[h], kk.x, -m0[h]));
                    float a1 = __builtin_amdgcn_exp2f(fmaf(q0[h], kk.y, -m0[h]));
                    float a2 = __builtin_amdgcn_exp2f(fmaf(q0[h], kk.z, -m0[h]));
                    float a3 = __builtin_amdgcn_exp2f(fmaf(q0[h], kk.w, -m0[h]));
                    S10[h] += (a0 + a1) + (a2 + a3);
                    S20[h] += (a0 * vq.x + a1 * vq.y) + (a2 * vq.z + a3 * vq.w);
                    float b0 = __builtin_amdgcn_exp2f(fmaf(q1[h], kk.x, -m1[h]));
                    float b1 = __builtin_amdgcn_exp2f(fmaf(q1[h], kk.y, -m1[h]));
                    float b2 = __builtin_amdgcn_exp2f(fmaf(q1[h], kk.z, -m1[h]));
                    float b3 = __builtin_amdgcn_exp2f(fmaf(q1[h], kk.w, -m1[h]));
                    S11[h] += (b0 + b1) + (b2 + b3);
                    S21[h] += (b0 * vq.x + b1 * vq.y) + (b2 * vq.z + b3 * vq.w);
                }
            }
#pragma unroll
            for (int h = 0; h < NH; ++h)
                for (int o = 1; o < JSL; o <<= 1) {
                    S10[h] += __shfl_xor(S10[h], o);
                    S11[h] += __shfl_xor(S11[h], o);
                    S20[h] += __shfl_xor(S20[h], o);
                    S21[h] += __shfl_xor(S21[h], o);
                }
            if (sl == 0 && valid) {
#pragma unroll
                for (int h = 0; h < NH; ++h) {
                    atomicAdd(&S1t[(b * NH + h) * G + i0],     S10[h]);
                    atomicAdd(&S1t[(b * NH + h) * G + i0 + 1], S11[h]);
                    atomicAdd(&S2t[(b * NH + h) * G + i0],     S20[h]);
                    atomicAdd(&S2t[(b * NH + h) * G + i0 + 1], S21[h]);
                }
            }
        }
        gg.sync();

        // ---- combine phase: one thread per (b,i,h-slot of 8) ----
        {
            const int RNG = NB * G * 8;
            const int iters = (RNG + T - 1) / T;
            for (int itn = 0; itn < iters; ++itn) {
                int idx = gt + itn * T;
                bool act = idx < RNG;
                int hs = idx & 7, rest = idx >> 3;
                int b = 0, i = 0;
                float term = 0.f;
                if (act) {
                    b = rest / G;
                    i = rest - b * G;
                    if (hs < NH) {
                        float S1 = S1t[(b * NH + hs) * G + i];
                        float S2 = S2t[(b * NH + hs) * G + i];
                        float xi = hin[b * G + i];
                        float qq  = xi * WQ[hs * G + i];
                        float kli = xi * WK[hs * G + i] * LOG2E;
                        float vvi = xi * WV[hs * G + i];
                        float kx = dec(km[(b * NH + hs) * 2]);
                        float kn = dec(km[(b * NH + hs) * 2 + 1]);
                        float mm = fmaxf(qq * kx, qq * kn);
                        float eii = __builtin_amdgcn_exp2f(fmaf(qq, kli, -mm));
                        term = W0[hs] * (S2 - eii * vvi) / S1;
                    }
                }
                term += __shfl_xor(term, 1);
                term += __shfl_xor(term, 2);
                term += __shfl_xor(term, 4);
                if (tid < 4) ((float*)sls)[tid] = 0.f;
                __syncthreads();
                int fb = ((bid * 256 + itn * T) >> 3) / G;   // first b in block
                if (act && hs == 0) {
                    abuf[b * G + i] = term;
                    int slot = b - fb;                        // 0 or 1
                    atomicAdd(&sls[slot][0], term);
                    atomicAdd(&sls[slot][1], term * term);
                }
                __syncthreads();
                if (tid < 2) {
                    int bb = fb + tid;
                    if (bb < NB) {
                        atomicAdd(&st[bb * 2 + 0], sls[tid][0]);
                        atomicAdd(&st[bb * 2 + 1], sls[tid][1]);
                    }
                }
                __syncthreads();
            }
        }
        gg.sync();

        // ---- ln apply (+ next-layer k minmax, + zero S totals) ----
        {
            const float* WKn = (l < 2) ? WKa[l + 1] : WK1;
            unsigned* kmn_ = kmm + (l + 1 < 3 ? l + 1 : 0) * NB * NH * 2;
            const int RNG = NB * G;
            const int iters = (RNG + T - 1) / T;
            for (int itn = 0; itn < iters; ++itn) {
                int idx = gt + itn * T;
                bool act = idx < RNG;
                int b = 0, i = 0;
                float hv = 0.f;
                if (act) {
                    b = idx / G;
                    i = idx - b * G;
                    float S = st[b * 2], SS = st[b * 2 + 1];
                    float mean = S / (float)G;
                    float var  = fmaxf((SS - S * mean) / (float)(G - 1), 0.f);
                    float inv  = 1.f / (sqrtf(var) + LN_EPS);
                    float v = abuf[idx];
                    hv = hin[idx] + lna[i] * (v - mean) * inv + lnb[i];
                    hbuf[idx] = hv;
                }
                if (l < 2) {
                    if (tid < 2 * NH) {
                        lmx[tid / NH][tid % NH] = 0u;
                        lmn[tid / NH][tid % NH] = 0xFFFFFFFFu;
                    }
                    __syncthreads();
                    int fb = (bid * 256 + itn * T) / G;
                    if (act) {
                        int slot = b - fb;
#pragma unroll
                        for (int h = 0; h < NH; ++h) {
                            unsigned e = enc(hv * WKn[h * G + i] * LOG2E);
                            atomicMax(&lmx[slot][h], e);
                            atomicMin(&lmn[slot][h], e);
                        }
                    }
                    __syncthreads();
                    if (tid < 2 * NH) {
                        int slot = tid / NH, h = tid - slot * NH;
                        int bb = fb + slot;
                        if (bb < NB) {
                            if (lmx[slot][h] != 0u)
                                atomicMax(&kmn_[(bb * NH + h) * 2], lmx[slot][h]);
                            if (lmn[slot][h] != 0xFFFFFFFFu)
                                atomicMin(&kmn_[(bb * NH + h) * 2 + 1], lmn[slot][h]);
                        }
                    }
                    __syncthreads();
                }
            }
            if (l < 2)
                for (int z = gt; z < NB * NH * G; z += T) { S1t[z] = 0.f; S2t[z] = 0.f; }
        }
        gg.sync();
    }

    // ---- logits: one wave per (c,b) ----
    for (int it = wid; it < NC * NB; it += NW) {
        int c = it % NC, b = it / NC;
        const float4* h4 = reinterpret_cast<const float4*>(hbuf + b * G);
        const float4* w4 = reinterpret_cast<const float4*>(fcw + (size_t)c * G);
        float s = 0.f;
        for (int k = lane; k < 427; k += 64) {
            float4 a = h4[k], w = w4[k];
            s += (a.x * w.x + a.y * w.y) + (a.z * w.z + a.w * w.w);
        }
        for (int o = 32; o; o >>= 1) s += __shfl_down(s, o);
        if (lane == 0) lgt[b * NC + c] = s + fcb[c];
    }
    gg.sync();

    // ---- log_softmax: one wave per batch row ----
    for (int it = wid; it < NB; it += NW) {
        float lv = (lane < NC) ? lgt[it * NC + lane] : -INFINITY;
        float mm = lv;
        for (int o = 32; o; o >>= 1) mm = fmaxf(mm, __shfl_xor(mm, o));
        float e = (lane < NC) ? expf(lv - mm) : 0.f;
        float se = e;
        for (int o = 32; o; o >>= 1) se += __shfl_xor(se, o);
        if (lane < NC) outp[it * NC + lane] = lv - mm - logf(se);
    }
}

// ---------------------------------------------------------------------------
extern "C" void kernel_launch(void* const* d_in, const int* in_sizes, int n_in,
                              void* d_out, int out_size, void* d_ws, size_t ws_size,
                              hipStream_t stream)
{
    const float* x    = (const float*)d_in[0];
    const float* WQ1  = (const float*)d_in[1];
    const float* WK1  = (const float*)d_in[2];
    const float* WV1  = (const float*)d_in[3];
    const float* W01  = (const float*)d_in[4];
    const float* WQ2  = (const float*)d_in[5];
    const float* WK2  = (const float*)d_in[6];
    const float* WV2  = (const float*)d_in[7];
    const float* W02  = (const float*)d_in[8];
    const float* WQ3  = (const float*)d_in[9];
    const float* WK3  = (const float*)d_in[10];
    const float* WV3  = (const float*)d_in[11];
    const float* W03  = (const float*)d_in[12];
    const float* lna  = (const float*)d_in[13];
    const float* lnb  = (const float*)d_in[14];
    const float* fcw  = (const float*)d_in[15];
    const float* fcb  = (const float*)d_in[16];
    float* outp = (float*)d_out;

    float*    abuf  = (float*)d_ws;                     // [NB,G]
    float*    hbuf  = abuf + (size_t)NB * G;            // [NB,G]
    float*    lgt   = hbuf + (size_t)NB * G;            // [NB,NC]
    float*    stats = lgt + NB * NC;                    // 3 x [NB,2]
    unsigned* kmm   = (unsigned*)(stats + 3 * NB * 2);  // 3 x [NB,NH,2]
    float*    S1t   = (float*)(kmm + 3 * NB * NH * 2);  // [NB,NH,G]
    float*    S2t   = S1t + (size_t)NB * NH * G;        // [NB,NH,G]

    int maxB = 0;
    if (hipOccupancyMaxActiveBlocksPerMultiprocessor(&maxB, fused, 256, 0)
            != hipSuccess || maxB < 1)
        maxB = 4;
    int grid = maxB * 256;          // 256 CUs
    if (grid > 1024) grid = 1024;   // 4 blocks/CU is plenty; keeps sync cheap

    void* args[] = {
        (void*)&x,
        (void*)&WQ1, (void*)&WK1, (void*)&WV1, (void*)&W01,
        (void*)&WQ2, (void*)&WK2, (void*)&WV2, (void*)&W02,
        (void*)&WQ3, (void*)&WK3, (void*)&WV3, (void*)&W03,
        (void*)&lna, (void*)&lnb, (void*)&fcw, (void*)&fcb,
        (void*)&outp,
        (void*)&abuf, (void*)&hbuf, (void*)&lgt,
        (void*)&stats, (void*)&kmm, (void*)&S1t, (void*)&S2t
    };
    hipLaunchCooperativeKernel(fused, dim3(grid), dim3(256), args, 0, stream);
}

// Round 7
// 349.288 us; speedup vs baseline: 2.7289x; 2.7289x over previous
//
#include <hip/hip_runtime.h>
#include <math.h>

#define G      1708
#define CH     427          // float4 chunks per row
#define NH     5
#define NB     16
#define NC     34
#define JB3    3            // j-splits in partial phase
#define LN_EPS 1e-6f
#define LOG2E  1.4426950408889634f

// ---------------------------------------------------------------------------
// Rank-1 score: s_ij = q_i*k_j  =>  exact row max m_i = max(q_i*kmax, q_i*kmin)
// (kmax/kmin per (b,h)).  Partial softmax sums over j-chunks with the same m_i
// add exactly.  q/k(log2)/v tables precomputed per layer in global memory so
// the partial kernel reads them with UNIFORM (scalar-pipe) loads.
// ---------------------------------------------------------------------------

// block reduce NH (max,min) pairs over 8 waves (512 threads), write kmm[b]
__device__ __forceinline__ void minmax_reduce_write(
    float* lmx, float* lmn, float* __restrict__ kmm, int b, int tid)
{
    __shared__ float rmx[NH][8], rmn[NH][8];
#pragma unroll
    for (int h = 0; h < NH; ++h)
        for (int o = 1; o < 64; o <<= 1) {
            lmx[h] = fmaxf(lmx[h], __shfl_xor(lmx[h], o));
            lmn[h] = fminf(lmn[h], __shfl_xor(lmn[h], o));
        }
    if ((tid & 63) == 0) {
#pragma unroll
        for (int h = 0; h < NH; ++h) {
            rmx[h][tid >> 6] = lmx[h];
            rmn[h][tid >> 6] = lmn[h];
        }
    }
    __syncthreads();
    if (tid < NH) {
        float mx = rmx[tid][0], mn = rmn[tid][0];
#pragma unroll
        for (int w = 1; w < 8; ++w) {
            mx = fmaxf(mx, rmx[tid][w]);
            mn = fminf(mn, rmn[tid][w]);
        }
        kmm[(b * NH + tid) * 2 + 0] = mx;
        kmm[(b * NH + tid) * 2 + 1] = mn;
    }
}

// ---------------------------------------------------------------------------
// Layer-1 table build: qt/kt/vt = x*WQ, x*WK*log2e, x*WV ; kmm min/max of kt.
// grid NB, 512 threads.
// ---------------------------------------------------------------------------
__global__ __launch_bounds__(512) void build_tables(
    const float* __restrict__ hin, const float* __restrict__ WQ,
    const float* __restrict__ WK, const float* __restrict__ WV,
    float* __restrict__ qt, float* __restrict__ kt, float* __restrict__ vt,
    float* __restrict__ kmm)
{
    const int b = blockIdx.x, tid = threadIdx.x;
    float lmx[NH], lmn[NH];
#pragma unroll
    for (int h = 0; h < NH; ++h) { lmx[h] = -INFINITY; lmn[h] = INFINITY; }
    for (int i = tid; i < G; i += 512) {
        float hv = hin[b * G + i];
#pragma unroll
        for (int h = 0; h < NH; ++h) {
            size_t bh = (size_t)(b * NH + h) * G + i;
            float kl = hv * WK[(size_t)h * G + i] * LOG2E;
            qt[bh] = hv * WQ[(size_t)h * G + i];
            kt[bh] = kl;
            vt[bh] = hv * WV[(size_t)h * G + i];
            lmx[h] = fmaxf(lmx[h], kl);
            lmn[h] = fminf(lmn[h], kl);
        }
    }
    __syncthreads();
    minmax_reduce_write(lmx, lmn, kmm, b, tid);
}

// ---------------------------------------------------------------------------
// Partial sums for one (i-chunk, h, j-third, b).  One thread per i.
// k/v reads are block-uniform -> scalar loads; no LDS, no barriers.
// grid (7, NH*JB3, NB) = 1680 blocks, 256 threads.
// ---------------------------------------------------------------------------
__global__ __launch_bounds__(256) void attn_partial(
    const float* __restrict__ qt, const float* __restrict__ kt,
    const float* __restrict__ vt, const float* __restrict__ kmm,
    float* __restrict__ S1p, float* __restrict__ S2p)
{
    const int b  = blockIdx.z;
    const int h  = blockIdx.y % NH;
    const int jb = blockIdx.y / NH;
    const int tid = threadIdx.x;
    const int i  = blockIdx.x * 256 + tid;
    const bool act = i < G;

    const size_t bh = (size_t)(b * NH + h) * G;
    const float q = act ? qt[bh + i] : 0.f;
    const float kx = kmm[(b * NH + h) * 2 + 0];
    const float kn = kmm[(b * NH + h) * 2 + 1];
    const float m = fmaxf(q * kx, q * kn);

    const float4* k4 = reinterpret_cast<const float4*>(kt + bh);
    const float4* v4 = reinterpret_cast<const float4*>(vt + bh);
    int c0, c1;
    if (jb == 0)      { c0 = 0;   c1 = 143; }
    else if (jb == 1) { c0 = 143; c1 = 285; }
    else              { c0 = 285; c1 = 427; }

    float S1 = 0.f, S2 = 0.f;
#pragma unroll 2
    for (int c = c0; c < c1; ++c) {
        float4 kk = k4[c];   // uniform -> s_load_dwordx4
        float4 vq = v4[c];
        float e0 = __builtin_amdgcn_exp2f(fmaf(q, kk.x, -m));
        float e1 = __builtin_amdgcn_exp2f(fmaf(q, kk.y, -m));
        float e2 = __builtin_amdgcn_exp2f(fmaf(q, kk.z, -m));
        float e3 = __builtin_amdgcn_exp2f(fmaf(q, kk.w, -m));
        S1 += (e0 + e1) + (e2 + e3);
        S2 += (e0 * vq.x + e1 * vq.y) + (e2 * vq.z + e3 * vq.w);
    }
    if (act) {
        size_t p = ((size_t)(jb * NB + b) * NH + h) * G + i;
        S1p[p] = S1;
        S2p[p] = S2;
    }
}

// ---------------------------------------------------------------------------
// Per-layer epilogue, one block per b (512 threads):
//   gather partials -> a_i (diag-corrected, head-summed) -> LN stats ->
//   h_out = hin + ln(a) -> next layer's q/k/v tables + kmin/kmax.
// No atomics: block owns the whole row b.
// ---------------------------------------------------------------------------
__global__ __launch_bounds__(512) void combine_ln(
    const float* __restrict__ hin, const float* __restrict__ qt,
    const float* __restrict__ kt, const float* __restrict__ vt,
    const float* __restrict__ kmm, const float* __restrict__ W0,
    const float* __restrict__ S1p, const float* __restrict__ S2p,
    const float* __restrict__ lna, const float* __restrict__ lnb,
    float* __restrict__ hout,
    const float* __restrict__ WQn, const float* __restrict__ WKn,
    const float* __restrict__ WVn,
    float* __restrict__ qtn, float* __restrict__ ktn, float* __restrict__ vtn,
    float* __restrict__ kmmn)
{
    const int b = blockIdx.x, tid = threadIdx.x;
    __shared__ float arow[G];
    __shared__ float red[8], rss[8];

    for (int i = tid; i < G; i += 512) {
        float acc = 0.f;
#pragma unroll
        for (int h = 0; h < NH; ++h) {
            float S1 = 0.f, S2 = 0.f;
#pragma unroll
            for (int jb = 0; jb < JB3; ++jb) {
                size_t p = ((size_t)(jb * NB + b) * NH + h) * G + i;
                S1 += S1p[p];
                S2 += S2p[p];
            }
            size_t bh = (size_t)(b * NH + h) * G + i;
            float q = qt[bh], kli = kt[bh], vvi = vt[bh];
            float kx = kmm[(b * NH + h) * 2 + 0];
            float kn = kmm[(b * NH + h) * 2 + 1];
            float m  = fmaxf(q * kx, q * kn);
            float eii = __builtin_amdgcn_exp2f(fmaf(q, kli, -m));
            acc += W0[h] * (S2 - eii * vvi) / S1;
        }
        arow[i] = acc;
    }
    __syncthreads();

    float s = 0.f, ss = 0.f;
    for (int i = tid; i < G; i += 512) {
        float v = arow[i];
        s += v;
        ss += v * v;
    }
    for (int o = 1; o < 64; o <<= 1) {
        s  += __shfl_xor(s, o);
        ss += __shfl_xor(ss, o);
    }
    if ((tid & 63) == 0) { red[tid >> 6] = s; rss[tid >> 6] = ss; }
    __syncthreads();
    float S = 0.f, SS = 0.f;
#pragma unroll
    for (int w = 0; w < 8; ++w) { S += red[w]; SS += rss[w]; }
    const float mean = S / (float)G;
    const float var  = fmaxf((SS - S * mean) / (float)(G - 1), 0.f);
    const float inv  = 1.f / (sqrtf(var) + LN_EPS);

    float lmx[NH], lmn[NH];
#pragma unroll
    for (int h = 0; h < NH; ++h) { lmx[h] = -INFINITY; lmn[h] = INFINITY; }

    const bool more = (WQn != nullptr);
    for (int i = tid; i < G; i += 512) {
        float v  = arow[i];
        float hv = hin[b * G + i] + lna[i] * (v - mean) * inv + lnb[i];
        hout[b * G + i] = hv;
        if (more) {
#pragma unroll
            for (int h = 0; h < NH; ++h) {
                size_t bh = (size_t)(b * NH + h) * G + i;
                float kl = hv * WKn[(size_t)h * G + i] * LOG2E;
                qtn[bh] = hv * WQn[(size_t)h * G + i];
                ktn[bh] = kl;
                vtn[bh] = hv * WVn[(size_t)h * G + i];
                lmx[h] = fmaxf(lmx[h], kl);
                lmn[h] = fminf(lmn[h], kl);
            }
        }
    }
    if (more) {
        __syncthreads();
        minmax_reduce_write(lmx, lmn, kmmn, b, tid);
    }
}

// ---------------------------------------------------------------------------
// logits = h @ fcw.T + fcb ; out = log_softmax(logits).  One block per b.
// ---------------------------------------------------------------------------
__global__ __launch_bounds__(256) void fc_lsm(
    const float* __restrict__ h, const float* __restrict__ fw,
    const float* __restrict__ fb, float* __restrict__ out)
{
    const int b = blockIdx.x, tid = threadIdx.x;
    const int w = tid >> 6, lane = tid & 63;
    __shared__ float hrow[G];
    __shared__ float lg[NC];
    for (int j = tid; j < G; j += 256) hrow[j] = h[(size_t)b * G + j];
    __syncthreads();

    const float4* h4 = reinterpret_cast<const float4*>(hrow);
    for (int c = w; c < NC; c += 4) {
        const float4* w4 = reinterpret_cast<const float4*>(fw + (size_t)c * G);
        float s = 0.f;
        for (int k = lane; k < CH; k += 64) {
            float4 a = h4[k], ww = w4[k];
            s += (a.x * ww.x + a.y * ww.y) + (a.z * ww.z + a.w * ww.w);
        }
        for (int o = 32; o; o >>= 1) s += __shfl_down(s, o);
        if (lane == 0) lg[c] = s + fb[c];
    }
    __syncthreads();

    if (tid < 64) {
        float l = (tid < NC) ? lg[tid] : -INFINITY;
        float mm = l;
        for (int o = 32; o; o >>= 1) mm = fmaxf(mm, __shfl_xor(mm, o));
        float e = (tid < NC) ? expf(l - mm) : 0.f;
        float se = e;
        for (int o = 32; o; o >>= 1) se += __shfl_xor(se, o);
        if (tid < NC) out[(size_t)b * NC + tid] = l - mm - logf(se);
    }
}

// ---------------------------------------------------------------------------
extern "C" void kernel_launch(void* const* d_in, const int* in_sizes, int n_in,
                              void* d_out, int out_size, void* d_ws, size_t ws_size,
                              hipStream_t stream)
{
    const float* x    = (const float*)d_in[0];
    const float* WQ1  = (const float*)d_in[1];
    const float* WK1  = (const float*)d_in[2];
    const float* WV1  = (const float*)d_in[3];
    const float* W01  = (const float*)d_in[4];
    const float* WQ2  = (const float*)d_in[5];
    const float* WK2  = (const float*)d_in[6];
    const float* WV2  = (const float*)d_in[7];
    const float* W02  = (const float*)d_in[8];
    const float* WQ3  = (const float*)d_in[9];
    const float* WK3  = (const float*)d_in[10];
    const float* WV3  = (const float*)d_in[11];
    const float* W03  = (const float*)d_in[12];
    const float* lna  = (const float*)d_in[13];
    const float* lnb  = (const float*)d_in[14];
    const float* fcw  = (const float*)d_in[15];
    const float* fcb  = (const float*)d_in[16];
    float* out = (float*)d_out;

    const size_t NBHG = (size_t)NB * NH * G;
    float* qt0 = (float*)d_ws;
    float* kt0 = qt0 + NBHG;
    float* vt0 = kt0 + NBHG;
    float* qt1 = vt0 + NBHG;
    float* kt1 = qt1 + NBHG;
    float* vt1 = kt1 + NBHG;
    float* S1p = vt1 + NBHG;            // [JB3, NB, NH, G]
    float* S2p = S1p + JB3 * NBHG;
    float* h1  = S2p + JB3 * NBHG;
    float* h2  = h1 + (size_t)NB * G;
    float* h3  = h2 + (size_t)NB * G;
    float* kmmA = h3 + (size_t)NB * G;  // [NB, NH, 2]
    float* kmmB = kmmA + NB * NH * 2;

    const dim3 pgrid(7, NH * JB3, NB);  // 1680 blocks

    build_tables<<<NB, 512, 0, stream>>>(x, WQ1, WK1, WV1, qt0, kt0, vt0, kmmA);

    attn_partial<<<pgrid, 256, 0, stream>>>(qt0, kt0, vt0, kmmA, S1p, S2p);
    combine_ln<<<NB, 512, 0, stream>>>(x, qt0, kt0, vt0, kmmA, W01, S1p, S2p,
                                       lna, lnb, h1, WQ2, WK2, WV2,
                                       qt1, kt1, vt1, kmmB);

    attn_partial<<<pgrid, 256, 0, stream>>>(qt1, kt1, vt1, kmmB, S1p, S2p);
    combine_ln<<<NB, 512, 0, stream>>>(h1, qt1, kt1, vt1, kmmB, W02, S1p, S2p,
                                       lna, lnb, h2, WQ3, WK3, WV3,
                                       qt0, kt0, vt0, kmmA);

    attn_partial<<<pgrid, 256, 0, stream>>>(qt0, kt0, vt0, kmmA, S1p, S2p);
    combine_ln<<<NB, 512, 0, stream>>>(h2, qt0, kt0, vt0, kmmA, W03, S1p, S2p,
                                       lna, lnb, h3, nullptr, nullptr, nullptr,
                                       nullptr, nullptr, nullptr, nullptr);

    fc_lsm<<<NB, 256, 0, stream>>>(h3, fcw, fcb, out);
}

// Round 8
// 260.773 us; speedup vs baseline: 3.6551x; 1.3394x over previous
//
#include <hip/hip_runtime.h>
#include <math.h>

#define G      1708
#define GP     1728         // padded table row stride (128-B aligned rows)
#define C4     427          // float4 chunks per row (1708/4)
#define NH     5
#define NB     16
#define NC     34
#define CHK    244          // G/7
#define NCK    7
#define ITR    4            // i per thread
#define JSL    8            // j-slices per i-group
#define IPB    128          // i per block = (256/JSL)*ITR
#define ICH    14           // ceil(G/IPB)
#define LN_EPS 1e-6f
#define LOG2E  1.4426950408889634f

// ---------------------------------------------------------------------------
// Rank-1 score: s_ij = q_i*k_j => exact row max m_i = max(q_i*kmax, q_i*kmin).
// Per-layer q/k(log2)/v tables in global memory (stride GP). Attention blocks
// own one (b,h,i-chunk) and the FULL j-range -> complete S1/S2 in-block, no
// partial arrays. Loads in the hot loop are thread-varying (vector path, L1).
// ---------------------------------------------------------------------------

// block (256 thr) reduce of NH (max,min) pairs -> kmmp[chunk][b][h][2]
__device__ __forceinline__ void minmax_write(
    float* lmx, float* lmn, float* __restrict__ kmmp, int c, int b, int tid)
{
    __shared__ float rmx[NH][4], rmn[NH][4];
#pragma unroll
    for (int h = 0; h < NH; ++h)
        for (int o = 1; o < 64; o <<= 1) {
            lmx[h] = fmaxf(lmx[h], __shfl_xor(lmx[h], o));
            lmn[h] = fminf(lmn[h], __shfl_xor(lmn[h], o));
        }
    if ((tid & 63) == 0) {
#pragma unroll
        for (int h = 0; h < NH; ++h) {
            rmx[h][tid >> 6] = lmx[h];
            rmn[h][tid >> 6] = lmn[h];
        }
    }
    __syncthreads();
    if (tid < NH) {
        float mx = fmaxf(fmaxf(rmx[tid][0], rmx[tid][1]), fmaxf(rmx[tid][2], rmx[tid][3]));
        float mn = fminf(fminf(rmn[tid][0], rmn[tid][1]), fminf(rmn[tid][2], rmn[tid][3]));
        kmmp[((c * NB + b) * NH + tid) * 2 + 0] = mx;
        kmmp[((c * NB + b) * NH + tid) * 2 + 1] = mn;
    }
}

// ---------------------------------------------------------------------------
// Layer-1 table build. grid (7, NB), 256 thr (244 active).
// ---------------------------------------------------------------------------
__global__ __launch_bounds__(256) void build_tables(
    const float* __restrict__ hin, const float* __restrict__ WQ,
    const float* __restrict__ WK, const float* __restrict__ WV,
    float* __restrict__ qt, float* __restrict__ kt, float* __restrict__ vt,
    float* __restrict__ kmmp)
{
    const int c = blockIdx.x, b = blockIdx.y, tid = threadIdx.x;
    const int i = c * CHK + tid;
    const bool act = tid < CHK;
    float lmx[NH], lmn[NH];
#pragma unroll
    for (int h = 0; h < NH; ++h) { lmx[h] = -INFINITY; lmn[h] = INFINITY; }
    if (act) {
        float hv = hin[b * G + i];
#pragma unroll
        for (int h = 0; h < NH; ++h) {
            size_t bh = (size_t)(b * NH + h) * GP + i;
            float kl = hv * WK[(size_t)h * G + i] * LOG2E;
            qt[bh] = hv * WQ[(size_t)h * G + i];
            kt[bh] = kl;
            vt[bh] = hv * WV[(size_t)h * G + i];
            lmx[h] = kl;
            lmn[h] = kl;
        }
    }
    minmax_write(lmx, lmn, kmmp, c, b, tid);
}

// ---------------------------------------------------------------------------
// Per-head attention: full j-range per block. grid (14, NH, NB), 256 thr.
// ph[b,h,i] = W0[h]*(S2 - e_ii*v_i)/S1
// ---------------------------------------------------------------------------
__global__ __launch_bounds__(256) void attn_heads(
    const float* __restrict__ qt, const float* __restrict__ kt,
    const float* __restrict__ vt, const float* __restrict__ kmmp,
    const float* __restrict__ W0, float* __restrict__ ph)
{
    const int b = blockIdx.z, h = blockIdx.y, ic = blockIdx.x;
    const int tid = threadIdx.x;
    const int ig = tid >> 3, sl = tid & 7;
    const int i0 = ic * IPB + ig * ITR;
    const bool valid = i0 < G;               // G%4==0, i0%4==0
    const int is = valid ? i0 : 0;

    // reduce per-chunk kmin/kmax partials
    float kx = -INFINITY, kn = INFINITY;
#pragma unroll
    for (int c = 0; c < NCK; ++c) {
        kx = fmaxf(kx, kmmp[((c * NB + b) * NH + h) * 2 + 0]);
        kn = fminf(kn, kmmp[((c * NB + b) * NH + h) * 2 + 1]);
    }

    const size_t base = (size_t)(b * NH + h) * GP;
    const float4 q4 = *reinterpret_cast<const float4*>(qt + base + is);
    float q[ITR] = {q4.x, q4.y, q4.z, q4.w};
    float m[ITR], S1[ITR], S2[ITR];
#pragma unroll
    for (int r = 0; r < ITR; ++r) {
        m[r]  = fmaxf(q[r] * kx, q[r] * kn);
        S1[r] = 0.f;
        S2[r] = 0.f;
    }

    const float4* k4 = reinterpret_cast<const float4*>(kt + base);
    const float4* v4 = reinterpret_cast<const float4*>(vt + base);
#pragma unroll 2
    for (int c = sl; c < C4; c += JSL) {
        float4 kk = k4[c];
        float4 vq = v4[c];
#pragma unroll
        for (int r = 0; r < ITR; ++r) {
            float qq = q[r], mm = m[r];
            float e0 = __builtin_amdgcn_exp2f(fmaf(qq, kk.x, -mm));
            float e1 = __builtin_amdgcn_exp2f(fmaf(qq, kk.y, -mm));
            float e2 = __builtin_amdgcn_exp2f(fmaf(qq, kk.z, -mm));
            float e3 = __builtin_amdgcn_exp2f(fmaf(qq, kk.w, -mm));
            S1[r] += (e0 + e1) + (e2 + e3);
            S2[r] += (e0 * vq.x + e1 * vq.y) + (e2 * vq.z + e3 * vq.w);
        }
    }

#pragma unroll
    for (int r = 0; r < ITR; ++r) {
        S1[r] += __shfl_xor(S1[r], 1);
        S1[r] += __shfl_xor(S1[r], 2);
        S1[r] += __shfl_xor(S1[r], 4);
        S2[r] += __shfl_xor(S2[r], 1);
        S2[r] += __shfl_xor(S2[r], 2);
        S2[r] += __shfl_xor(S2[r], 4);
    }

    if (sl == 0 && valid) {
        const float w0h = W0[h];
        const float4 kt4 = *reinterpret_cast<const float4*>(kt + base + i0);
        const float4 vt4 = *reinterpret_cast<const float4*>(vt + base + i0);
        const float kli[ITR] = {kt4.x, kt4.y, kt4.z, kt4.w};
        const float vvi[ITR] = {vt4.x, vt4.y, vt4.z, vt4.w};
        float o[ITR];
#pragma unroll
        for (int r = 0; r < ITR; ++r) {
            float eii = __builtin_amdgcn_exp2f(fmaf(q[r], kli[r], -m[r]));
            o[r] = w0h * (S2[r] - eii * vvi[r]) / S1[r];
        }
        *reinterpret_cast<float4*>(ph + base + i0) =
            make_float4(o[0], o[1], o[2], o[3]);
    }
}

// ---------------------------------------------------------------------------
// Combine heads + partial LN stats. grid (7, NB), 256 thr (244 active).
// ---------------------------------------------------------------------------
__global__ __launch_bounds__(256) void combine_stats(
    const float* __restrict__ ph, float* __restrict__ abuf,
    float* __restrict__ statsp)
{
    const int c = blockIdx.x, b = blockIdx.y, tid = threadIdx.x;
    const int i = c * CHK + tid;
    const bool act = tid < CHK;
    float a = 0.f;
    if (act) {
#pragma unroll
        for (int h = 0; h < NH; ++h)
            a += ph[(size_t)(b * NH + h) * GP + i];
        abuf[b * G + i] = a;
    }
    float s = a, ss = a * a;
    for (int o = 1; o < 64; o <<= 1) {
        s  += __shfl_xor(s, o);
        ss += __shfl_xor(ss, o);
    }
    __shared__ float rs[4], rss[4];
    if ((tid & 63) == 0) { rs[tid >> 6] = s; rss[tid >> 6] = ss; }
    __syncthreads();
    if (tid == 0) {
        statsp[(b * NCK + c) * 2 + 0] = (rs[0] + rs[1]) + (rs[2] + rs[3]);
        statsp[(b * NCK + c) * 2 + 1] = (rss[0] + rss[1]) + (rss[2] + rss[3]);
    }
}

// ---------------------------------------------------------------------------
// LN apply + next-layer table build (+kminmax partials). grid (7, NB).
// WQn==nullptr -> last layer (no build).
// ---------------------------------------------------------------------------
__global__ __launch_bounds__(256) void ln_build(
    const float* __restrict__ hin, const float* __restrict__ abuf,
    const float* __restrict__ statsp,
    const float* __restrict__ lna, const float* __restrict__ lnb,
    float* __restrict__ hout,
    const float* __restrict__ WQn, const float* __restrict__ WKn,
    const float* __restrict__ WVn,
    float* __restrict__ qtn, float* __restrict__ ktn, float* __restrict__ vtn,
    float* __restrict__ kmmpn)
{
    const int c = blockIdx.x, b = blockIdx.y, tid = threadIdx.x;
    const int i = c * CHK + tid;
    const bool act = tid < CHK;

    float S = 0.f, SS = 0.f;
#pragma unroll
    for (int k = 0; k < NCK; ++k) {
        S  += statsp[(b * NCK + k) * 2 + 0];
        SS += statsp[(b * NCK + k) * 2 + 1];
    }
    const float mean = S / (float)G;
    const float var  = fmaxf((SS - S * mean) / (float)(G - 1), 0.f);
    const float inv  = 1.f / (sqrtf(var) + LN_EPS);

    float lmx[NH], lmn[NH];
#pragma unroll
    for (int h = 0; h < NH; ++h) { lmx[h] = -INFINITY; lmn[h] = INFINITY; }

    if (act) {
        float v  = abuf[b * G + i];
        float hv = hin[b * G + i] + lna[i] * (v - mean) * inv + lnb[i];
        hout[b * G + i] = hv;
        if (WQn != nullptr) {
#pragma unroll
            for (int h = 0; h < NH; ++h) {
                size_t bh = (size_t)(b * NH + h) * GP + i;
                float kl = hv * WKn[(size_t)h * G + i] * LOG2E;
                qtn[bh] = hv * WQn[(size_t)h * G + i];
                ktn[bh] = kl;
                vtn[bh] = hv * WVn[(size_t)h * G + i];
                lmx[h] = kl;
                lmn[h] = kl;
            }
        }
    }
    if (WQn != nullptr) minmax_write(lmx, lmn, kmmpn, c, b, tid);
}

// ---------------------------------------------------------------------------
__global__ __launch_bounds__(64) void logits_kernel(
    const float* __restrict__ h, const float* __restrict__ fw,
    const float* __restrict__ fb, float* __restrict__ logits)
{
    const int c = blockIdx.x, b = blockIdx.y;
    const int lane = threadIdx.x;
    const float4* h4 = reinterpret_cast<const float4*>(h + (size_t)b * G);
    const float4* w4 = reinterpret_cast<const float4*>(fw + (size_t)c * G);
    float s = 0.f;
    for (int k = lane; k < C4; k += 64) {
        float4 a = h4[k], w = w4[k];
        s += (a.x * w.x + a.y * w.y) + (a.z * w.z + a.w * w.w);
    }
    for (int o = 32; o; o >>= 1) s += __shfl_down(s, o);
    if (lane == 0) logits[(size_t)b * NC + c] = s + fb[c];
}

__global__ __launch_bounds__(64) void lsm_kernel(
    const float* __restrict__ logits, float* __restrict__ out)
{
    const int b = blockIdx.x, tid = threadIdx.x;
    float l = (tid < NC) ? logits[(size_t)b * NC + tid] : -INFINITY;
    float mm = l;
    for (int o = 32; o; o >>= 1) mm = fmaxf(mm, __shfl_xor(mm, o));
    float e = (tid < NC) ? expf(l - mm) : 0.f;
    float se = e;
    for (int o = 32; o; o >>= 1) se += __shfl_xor(se, o);
    if (tid < NC) out[(size_t)b * NC + tid] = l - mm - logf(se);
}

// ---------------------------------------------------------------------------
extern "C" void kernel_launch(void* const* d_in, const int* in_sizes, int n_in,
                              void* d_out, int out_size, void* d_ws, size_t ws_size,
                              hipStream_t stream)
{
    const float* x    = (const float*)d_in[0];
    const float* WQ1  = (const float*)d_in[1];
    const float* WK1  = (const float*)d_in[2];
    const float* WV1  = (const float*)d_in[3];
    const float* W01  = (const float*)d_in[4];
    const float* WQ2  = (const float*)d_in[5];
    const float* WK2  = (const float*)d_in[6];
    const float* WV2  = (const float*)d_in[7];
    const float* W02  = (const float*)d_in[8];
    const float* WQ3  = (const float*)d_in[9];
    const float* WK3  = (const float*)d_in[10];
    const float* WV3  = (const float*)d_in[11];
    const float* W03  = (const float*)d_in[12];
    const float* lna  = (const float*)d_in[13];
    const float* lnb  = (const float*)d_in[14];
    const float* fcw  = (const float*)d_in[15];
    const float* fcb  = (const float*)d_in[16];
    float* out = (float*)d_out;

    const size_t TSZ = (size_t)NB * NH * GP;   // one table
    float* qt0  = (float*)d_ws;
    float* kt0  = qt0 + TSZ;
    float* vt0  = kt0 + TSZ;
    float* qt1  = vt0 + TSZ;
    float* kt1  = qt1 + TSZ;
    float* vt1  = kt1 + TSZ;
    float* ph   = vt1 + TSZ;                   // [NB,NH,GP]
    float* abuf = ph + TSZ;                    // [NB,G]
    float* h1   = abuf + (size_t)NB * G;
    float* h2   = h1 + (size_t)NB * G;
    float* h3   = h2 + (size_t)NB * G;
    float* lgt  = h3 + (size_t)NB * G;         // [NB,NC]
    float* stp  = lgt + NB * NC;               // [NB,7,2]
    float* kmpA = stp + NB * NCK * 2;          // [7,NB,NH,2]
    float* kmpB = kmpA + NCK * NB * NH * 2;

    const dim3 egrid(NCK, NB);                 // (7,16)
    const dim3 agrid(ICH, NH, NB);             // (14,5,16) = 1120

    build_tables<<<egrid, 256, 0, stream>>>(x, WQ1, WK1, WV1, qt0, kt0, vt0, kmpA);

    attn_heads<<<agrid, 256, 0, stream>>>(qt0, kt0, vt0, kmpA, W01, ph);
    combine_stats<<<egrid, 256, 0, stream>>>(ph, abuf, stp);
    ln_build<<<egrid, 256, 0, stream>>>(x, abuf, stp, lna, lnb, h1,
                                        WQ2, WK2, WV2, qt1, kt1, vt1, kmpB);

    attn_heads<<<agrid, 256, 0, stream>>>(qt1, kt1, vt1, kmpB, W02, ph);
    combine_stats<<<egrid, 256, 0, stream>>>(ph, abuf, stp);
    ln_build<<<egrid, 256, 0, stream>>>(h1, abuf, stp, lna, lnb, h2,
                                        WQ3, WK3, WV3, qt0, kt0, vt0, kmpA);

    attn_heads<<<agrid, 256, 0, stream>>>(qt0, kt0, vt0, kmpA, W03, ph);
    combine_stats<<<egrid, 256, 0, stream>>>(ph, abuf, stp);
    ln_build<<<egrid, 256, 0, stream>>>(h2, abuf, stp, lna, lnb, h3,
                                        nullptr, nullptr, nullptr,
                                        nullptr, nullptr, nullptr, nullptr);

    logits_kernel<<<dim3(NC, NB), 64, 0, stream>>>(h3, fcw, fcb, lgt);
    lsm_kernel<<<NB, 64, 0, stream>>>(lgt, out);
}

// Round 9
// 260.655 us; speedup vs baseline: 3.6568x; 1.0005x over previous
//
#include <hip/hip_runtime.h>
#include <math.h>

#define G      1708
#define GP     1728         // padded per-head row stride
#define C4     427          // float4 chunks per row
#define NH     5
#define NB     16
#define NC     34
#define JSL    8            // j-slices per i-group
#define ITR    4            // i per thread
#define IPB    128          // i per block
#define ICH    14           // ceil(G/IPB)
#define LN_EPS 1e-6f
#define LOG2E  1.4426950408889634f

// ---------------------------------------------------------------------------
// Fused per-layer attention. Block = (i-chunk, head, batch). Each block:
//  (A) [layers 2/3] recombine prev layer's per-head rows -> a, row LN stats
//  (B) h = hprev + ln(a)  (layer1: h = x); build k*log2e and v rows in LDS;
//      block-local exact kmin/kmax (rank-1 row max: m_i = max(q*kmax,q*kmin))
//  (C) j-loop from LDS (double-buffered) -> S1,S2 -> per-head output ph.
// Block (h==0,ic==0) persists the combined h row for the next kernel.
// ---------------------------------------------------------------------------
template <bool FIRST>
__global__ __launch_bounds__(256) void attn_layer(
    const float* __restrict__ hprev, const float* __restrict__ php,
    const float* __restrict__ lna, const float* __restrict__ lnb,
    const float* __restrict__ WQ, const float* __restrict__ WK,
    const float* __restrict__ WV, const float* __restrict__ W0,
    float* __restrict__ ph, float* __restrict__ hcur)
{
    __shared__ __align__(16) float hrow[G];   // a, then h
    __shared__ __align__(16) float krow[G];
    __shared__ __align__(16) float vrow[G];
    __shared__ float red[8];

    const int ic = blockIdx.x, h = blockIdx.y, b = blockIdx.z;
    const int tid = threadIdx.x;

    const float4* hp4 = reinterpret_cast<const float4*>(hprev + (size_t)b * G);
    float4* hr4 = reinterpret_cast<float4*>(hrow);
    float4* kr4 = reinterpret_cast<float4*>(krow);
    float4* vr4 = reinterpret_cast<float4*>(vrow);

    float mean = 0.f, inv = 0.f;
    if constexpr (!FIRST) {
        // ---- phase A: combine heads, LN stats ----
        const float4* p0 = reinterpret_cast<const float4*>(php + ((size_t)b * NH + 0) * GP);
        const float4* p1 = reinterpret_cast<const float4*>(php + ((size_t)b * NH + 1) * GP);
        const float4* p2 = reinterpret_cast<const float4*>(php + ((size_t)b * NH + 2) * GP);
        const float4* p3 = reinterpret_cast<const float4*>(php + ((size_t)b * NH + 3) * GP);
        const float4* p4 = reinterpret_cast<const float4*>(php + ((size_t)b * NH + 4) * GP);
        float s = 0.f, ss = 0.f;
        for (int c = tid; c < C4; c += 256) {
            float4 a = p0[c], t;
            t = p1[c]; a.x += t.x; a.y += t.y; a.z += t.z; a.w += t.w;
            t = p2[c]; a.x += t.x; a.y += t.y; a.z += t.z; a.w += t.w;
            t = p3[c]; a.x += t.x; a.y += t.y; a.z += t.z; a.w += t.w;
            t = p4[c]; a.x += t.x; a.y += t.y; a.z += t.z; a.w += t.w;
            hr4[c] = a;
            s  += (a.x + a.y) + (a.z + a.w);
            ss += (a.x * a.x + a.y * a.y) + (a.z * a.z + a.w * a.w);
        }
        for (int o = 1; o < 64; o <<= 1) {
            s  += __shfl_xor(s, o);
            ss += __shfl_xor(ss, o);
        }
        if ((tid & 63) == 0) { red[tid >> 6] = s; red[4 + (tid >> 6)] = ss; }
        __syncthreads();
        float S  = (red[0] + red[1]) + (red[2] + red[3]);
        float SS = (red[4] + red[5]) + (red[6] + red[7]);
        mean = S / (float)G;
        float var = fmaxf((SS - S * mean) / (float)(G - 1), 0.f);
        inv = 1.f / (sqrtf(var) + LN_EPS);
    }

    // ---- phase B: h row, k/v tables, block-local kmin/kmax ----
    const float4* wk4 = reinterpret_cast<const float4*>(WK + (size_t)h * G);
    const float4* wv4 = reinterpret_cast<const float4*>(WV + (size_t)h * G);
    const float4* ga4 = reinterpret_cast<const float4*>(lna);
    const float4* gb4 = reinterpret_cast<const float4*>(lnb);
    float kmx = -INFINITY, kmn = INFINITY;
    for (int c = tid; c < C4; c += 256) {
        float4 hv;
        if constexpr (FIRST) {
            hv = hp4[c];
        } else {
            float4 a = hr4[c], hp = hp4[c], ga = ga4[c], gb = gb4[c];
            hv.x = hp.x + ga.x * (a.x - mean) * inv + gb.x;
            hv.y = hp.y + ga.y * (a.y - mean) * inv + gb.y;
            hv.z = hp.z + ga.z * (a.z - mean) * inv + gb.z;
            hv.w = hp.w + ga.w * (a.w - mean) * inv + gb.w;
        }
        hr4[c] = hv;
        float4 wk = wk4[c], wv = wv4[c], kl, vv;
        kl.x = hv.x * wk.x * LOG2E; kl.y = hv.y * wk.y * LOG2E;
        kl.z = hv.z * wk.z * LOG2E; kl.w = hv.w * wk.w * LOG2E;
        vv.x = hv.x * wv.x; vv.y = hv.y * wv.y;
        vv.z = hv.z * wv.z; vv.w = hv.w * wv.w;
        kr4[c] = kl;
        vr4[c] = vv;
        kmx = fmaxf(kmx, fmaxf(fmaxf(kl.x, kl.y), fmaxf(kl.z, kl.w)));
        kmn = fminf(kmn, fminf(fminf(kl.x, kl.y), fminf(kl.z, kl.w)));
    }
    for (int o = 1; o < 64; o <<= 1) {
        kmx = fmaxf(kmx, __shfl_xor(kmx, o));
        kmn = fminf(kmn, __shfl_xor(kmn, o));
    }
    __syncthreads();   // phase-A red reads done; LDS tables visible
    if ((tid & 63) == 0) { red[tid >> 6] = kmx; red[4 + (tid >> 6)] = kmn; }
    __syncthreads();
    kmx = fmaxf(fmaxf(red[0], red[1]), fmaxf(red[2], red[3]));
    kmn = fminf(fminf(red[4], red[5]), fminf(red[6], red[7]));

    // persist combined h row (one block per b)
    if (!FIRST && hcur != nullptr && h == 0 && ic == 0) {
        float4* hc4 = reinterpret_cast<float4*>(hcur + (size_t)b * G);
        for (int c = tid; c < C4; c += 256) hc4[c] = hr4[c];
    }

    // ---- phase C: softmax-weighted sums over j ----
    const int ig = tid >> 3, sl = tid & 7;
    const int i0 = ic * IPB + ig * ITR;
    const bool valid = i0 < G;          // G%4==0, i0%4==0
    const int is = valid ? i0 : 0;

    const float4 hq = hr4[is >> 2];
    const float4 wq = *reinterpret_cast<const float4*>(WQ + (size_t)h * G + is);
    float q[ITR] = {hq.x * wq.x, hq.y * wq.y, hq.z * wq.z, hq.w * wq.w};
    float m[ITR], S1[ITR], S2[ITR];
#pragma unroll
    for (int r = 0; r < ITR; ++r) {
        m[r]  = fmaxf(q[r] * kmx, q[r] * kmn);
        S1[r] = 0.f;
        S2[r] = 0.f;
    }

    float4 kk = kr4[sl], vq = vr4[sl];
    for (int c = sl;;) {
        const int cn = c + JSL;
        const bool more = cn < C4;
        float4 kkn, vqn;
        if (more) { kkn = kr4[cn]; vqn = vr4[cn]; }
#pragma unroll
        for (int r = 0; r < ITR; ++r) {
            float qq = q[r], mm = m[r];
            float e0 = __builtin_amdgcn_exp2f(fmaf(qq, kk.x, -mm));
            float e1 = __builtin_amdgcn_exp2f(fmaf(qq, kk.y, -mm));
            float e2 = __builtin_amdgcn_exp2f(fmaf(qq, kk.z, -mm));
            float e3 = __builtin_amdgcn_exp2f(fmaf(qq, kk.w, -mm));
            S1[r] += (e0 + e1) + (e2 + e3);
            S2[r] += (e0 * vq.x + e1 * vq.y) + (e2 * vq.z + e3 * vq.w);
        }
        if (!more) break;
        kk = kkn; vq = vqn; c = cn;
    }

#pragma unroll
    for (int r = 0; r < ITR; ++r) {
        S1[r] += __shfl_xor(S1[r], 1);
        S1[r] += __shfl_xor(S1[r], 2);
        S1[r] += __shfl_xor(S1[r], 4);
        S2[r] += __shfl_xor(S2[r], 1);
        S2[r] += __shfl_xor(S2[r], 2);
        S2[r] += __shfl_xor(S2[r], 4);
    }

    if (sl == 0 && valid) {
        const float w0h = W0[h];
        const float4 kt4 = kr4[i0 >> 2];
        const float4 vt4 = vr4[i0 >> 2];
        const float kli[ITR] = {kt4.x, kt4.y, kt4.z, kt4.w};
        const float vvi[ITR] = {vt4.x, vt4.y, vt4.z, vt4.w};
        float o[ITR];
#pragma unroll
        for (int r = 0; r < ITR; ++r) {
            float eii = __builtin_amdgcn_exp2f(fmaf(q[r], kli[r], -m[r]));
            o[r] = w0h * (S2[r] - eii * vvi[r]) / S1[r];
        }
        *reinterpret_cast<float4*>(ph + ((size_t)b * NH + h) * GP + i0) =
            make_float4(o[0], o[1], o[2], o[3]);
    }
}

// ---------------------------------------------------------------------------
// Final: combine layer-3 heads + LN -> h3 (LDS) -> fc -> log_softmax.
// One block per batch row.
// ---------------------------------------------------------------------------
__global__ __launch_bounds__(256) void fc_head(
    const float* __restrict__ hprev, const float* __restrict__ php,
    const float* __restrict__ lna, const float* __restrict__ lnb,
    const float* __restrict__ fcw, const float* __restrict__ fcb,
    float* __restrict__ out)
{
    __shared__ __align__(16) float hrow[G];
    __shared__ float red[8];
    __shared__ float lg[NC];

    const int b = blockIdx.x, tid = threadIdx.x;
    const float4* hp4 = reinterpret_cast<const float4*>(hprev + (size_t)b * G);
    float4* hr4 = reinterpret_cast<float4*>(hrow);

    const float4* p0 = reinterpret_cast<const float4*>(php + ((size_t)b * NH + 0) * GP);
    const float4* p1 = reinterpret_cast<const float4*>(php + ((size_t)b * NH + 1) * GP);
    const float4* p2 = reinterpret_cast<const float4*>(php + ((size_t)b * NH + 2) * GP);
    const float4* p3 = reinterpret_cast<const float4*>(php + ((size_t)b * NH + 3) * GP);
    const float4* p4 = reinterpret_cast<const float4*>(php + ((size_t)b * NH + 4) * GP);
    float s = 0.f, ss = 0.f;
    for (int c = tid; c < C4; c += 256) {
        float4 a = p0[c], t;
        t = p1[c]; a.x += t.x; a.y += t.y; a.z += t.z; a.w += t.w;
        t = p2[c]; a.x += t.x; a.y += t.y; a.z += t.z; a.w += t.w;
        t = p3[c]; a.x += t.x; a.y += t.y; a.z += t.z; a.w += t.w;
        t = p4[c]; a.x += t.x; a.y += t.y; a.z += t.z; a.w += t.w;
        hr4[c] = a;
        s  += (a.x + a.y) + (a.z + a.w);
        ss += (a.x * a.x + a.y * a.y) + (a.z * a.z + a.w * a.w);
    }
    for (int o = 1; o < 64; o <<= 1) {
        s  += __shfl_xor(s, o);
        ss += __shfl_xor(ss, o);
    }
    if ((tid & 63) == 0) { red[tid >> 6] = s; red[4 + (tid >> 6)] = ss; }
    __syncthreads();
    float S  = (red[0] + red[1]) + (red[2] + red[3]);
    float SS = (red[4] + red[5]) + (red[6] + red[7]);
    const float mean = S / (float)G;
    const float var  = fmaxf((SS - S * mean) / (float)(G - 1), 0.f);
    const float inv  = 1.f / (sqrtf(var) + LN_EPS);

    const float4* ga4 = reinterpret_cast<const float4*>(lna);
    const float4* gb4 = reinterpret_cast<const float4*>(lnb);
    for (int c = tid; c < C4; c += 256) {
        float4 a = hr4[c], hp = hp4[c], ga = ga4[c], gb = gb4[c];
        float4 hv;
        hv.x = hp.x + ga.x * (a.x - mean) * inv + gb.x;
        hv.y = hp.y + ga.y * (a.y - mean) * inv + gb.y;
        hv.z = hp.z + ga.z * (a.z - mean) * inv + gb.z;
        hv.w = hp.w + ga.w * (a.w - mean) * inv + gb.w;
        hr4[c] = hv;
    }
    __syncthreads();

    const int w = tid >> 6, lane = tid & 63;
    for (int c = w; c < NC; c += 4) {
        const float4* w4 = reinterpret_cast<const float4*>(fcw + (size_t)c * G);
        float acc = 0.f;
        for (int k = lane; k < C4; k += 64) {
            float4 a = hr4[k], ww = w4[k];
            acc += (a.x * ww.x + a.y * ww.y) + (a.z * ww.z + a.w * ww.w);
        }
        for (int o = 32; o; o >>= 1) acc += __shfl_down(acc, o);
        if (lane == 0) lg[c] = acc + fcb[c];
    }
    __syncthreads();

    if (tid < 64) {
        float l = (tid < NC) ? lg[tid] : -INFINITY;
        float mm = l;
        for (int o = 32; o; o >>= 1) mm = fmaxf(mm, __shfl_xor(mm, o));
        float e = (tid < NC) ? expf(l - mm) : 0.f;
        float se = e;
        for (int o = 32; o; o >>= 1) se += __shfl_xor(se, o);
        if (tid < NC) out[(size_t)b * NC + tid] = l - mm - logf(se);
    }
}

// ---------------------------------------------------------------------------
extern "C" void kernel_launch(void* const* d_in, const int* in_sizes, int n_in,
                              void* d_out, int out_size, void* d_ws, size_t ws_size,
                              hipStream_t stream)
{
    const float* x    = (const float*)d_in[0];
    const float* WQ1  = (const float*)d_in[1];
    const float* WK1  = (const float*)d_in[2];
    const float* WV1  = (const float*)d_in[3];
    const float* W01  = (const float*)d_in[4];
    const float* WQ2  = (const float*)d_in[5];
    const float* WK2  = (const float*)d_in[6];
    const float* WV2  = (const float*)d_in[7];
    const float* W02  = (const float*)d_in[8];
    const float* WQ3  = (const float*)d_in[9];
    const float* WK3  = (const float*)d_in[10];
    const float* WV3  = (const float*)d_in[11];
    const float* W03  = (const float*)d_in[12];
    const float* lna  = (const float*)d_in[13];
    const float* lnb  = (const float*)d_in[14];
    const float* fcw  = (const float*)d_in[15];
    const float* fcb  = (const float*)d_in[16];
    float* out = (float*)d_out;

    const size_t PHS = (size_t)NB * NH * GP;
    float* pha = (float*)d_ws;           // layer 1 / 3 per-head rows
    float* phb = pha + PHS;              // layer 2 per-head rows
    float* h1  = phb + PHS;              // [NB,G]
    float* h2  = h1 + (size_t)NB * G;    // [NB,G]

    const dim3 agrid(ICH, NH, NB);       // (14,5,16) = 1120 blocks

    attn_layer<true><<<agrid, 256, 0, stream>>>(
        x, nullptr, lna, lnb, WQ1, WK1, WV1, W01, pha, nullptr);
    attn_layer<false><<<agrid, 256, 0, stream>>>(
        x, pha, lna, lnb, WQ2, WK2, WV2, W02, phb, h1);
    attn_layer<false><<<agrid, 256, 0, stream>>>(
        h1, phb, lna, lnb, WQ3, WK3, WV3, W03, pha, h2);
    fc_head<<<NB, 256, 0, stream>>>(h2, pha, lna, lnb, fcw, fcb, out);
}

// Round 10
// 209.495 us; speedup vs baseline: 4.5498x; 1.2442x over previous
//
#include <hip/hip_runtime.h>
#include <math.h>

#define G      1708
#define GP     1728         // padded per-head row stride
#define C4     427          // float4 chunks per row
#define NH     5
#define NB     16
#define NC     34
#define JSL    8            // j-slices per i-group
#define ITR    2            // i per thread
#define IPB    64           // i per block
#define ICH    27           // ceil(G/IPB)
#define LN_EPS 1e-6f
#define LOG2E  1.4426950408889634f

// ---------------------------------------------------------------------------
// Fused per-layer attention. Block = (i-chunk, head, batch). Each block:
//  (A) [layers 2/3] recombine prev layer's per-head rows -> a, row LN stats
//      (identical redundant compute per block; deterministic)
//  (B) h = hprev + ln(a)  (layer1: h = x); build k*log2e, v rows in LDS;
//      block kmin/kmax (rank-1 exact row max: m_i = max(q*kmax, q*kmin))
//  (C) j-loop from LDS -> S1,S2 -> per-head output ph.
// grid (27,5,16)=2160 blocks, 20.5 KB LDS -> ~7 blocks/CU resident.
// ---------------------------------------------------------------------------
template <bool FIRST>
__global__ __launch_bounds__(256) void attn_layer(
    const float* __restrict__ hprev, const float* __restrict__ php,
    const float* __restrict__ lna, const float* __restrict__ lnb,
    const float* __restrict__ WQ, const float* __restrict__ WK,
    const float* __restrict__ WV, const float* __restrict__ W0,
    float* __restrict__ ph, float* __restrict__ hcur)
{
    __shared__ __align__(16) float hrow[G];   // a, then h
    __shared__ __align__(16) float krow[G];
    __shared__ __align__(16) float vrow[G];
    __shared__ float red[8];

    const int ic = blockIdx.x, h = blockIdx.y, b = blockIdx.z;
    const int tid = threadIdx.x;

    const float4* hp4 = reinterpret_cast<const float4*>(hprev + (size_t)b * G);
    float4* hr4 = reinterpret_cast<float4*>(hrow);
    float4* kr4 = reinterpret_cast<float4*>(krow);
    float4* vr4 = reinterpret_cast<float4*>(vrow);
    const float2* hr2 = reinterpret_cast<const float2*>(hrow);
    const float2* kr2 = reinterpret_cast<const float2*>(krow);
    const float2* vr2 = reinterpret_cast<const float2*>(vrow);

    float mean = 0.f, inv = 0.f;
    if constexpr (!FIRST) {
        // ---- phase A: combine heads, LN stats ----
        const float4* p0 = reinterpret_cast<const float4*>(php + ((size_t)b * NH + 0) * GP);
        const float4* p1 = reinterpret_cast<const float4*>(php + ((size_t)b * NH + 1) * GP);
        const float4* p2 = reinterpret_cast<const float4*>(php + ((size_t)b * NH + 2) * GP);
        const float4* p3 = reinterpret_cast<const float4*>(php + ((size_t)b * NH + 3) * GP);
        const float4* p4 = reinterpret_cast<const float4*>(php + ((size_t)b * NH + 4) * GP);
        float s = 0.f, ss = 0.f;
        for (int c = tid; c < C4; c += 256) {
            float4 a = p0[c], t;
            t = p1[c]; a.x += t.x; a.y += t.y; a.z += t.z; a.w += t.w;
            t = p2[c]; a.x += t.x; a.y += t.y; a.z += t.z; a.w += t.w;
            t = p3[c]; a.x += t.x; a.y += t.y; a.z += t.z; a.w += t.w;
            t = p4[c]; a.x += t.x; a.y += t.y; a.z += t.z; a.w += t.w;
            hr4[c] = a;
            s  += (a.x + a.y) + (a.z + a.w);
            ss += (a.x * a.x + a.y * a.y) + (a.z * a.z + a.w * a.w);
        }
        for (int o = 1; o < 64; o <<= 1) {
            s  += __shfl_xor(s, o);
            ss += __shfl_xor(ss, o);
        }
        if ((tid & 63) == 0) { red[tid >> 6] = s; red[4 + (tid >> 6)] = ss; }
        __syncthreads();
        float S  = (red[0] + red[1]) + (red[2] + red[3]);
        float SS = (red[4] + red[5]) + (red[6] + red[7]);
        mean = S / (float)G;
        float var = fmaxf((SS - S * mean) / (float)(G - 1), 0.f);
        inv = 1.f / (sqrtf(var) + LN_EPS);
    }

    // ---- phase B: h row, k/v tables, block kmin/kmax ----
    const float4* wk4 = reinterpret_cast<const float4*>(WK + (size_t)h * G);
    const float4* wv4 = reinterpret_cast<const float4*>(WV + (size_t)h * G);
    const float4* ga4 = reinterpret_cast<const float4*>(lna);
    const float4* gb4 = reinterpret_cast<const float4*>(lnb);
    float kmx = -INFINITY, kmn = INFINITY;
    for (int c = tid; c < C4; c += 256) {
        float4 hv;
        if constexpr (FIRST) {
            hv = hp4[c];
        } else {
            float4 a = hr4[c], hp = hp4[c], ga = ga4[c], gb = gb4[c];
            hv.x = hp.x + ga.x * (a.x - mean) * inv + gb.x;
            hv.y = hp.y + ga.y * (a.y - mean) * inv + gb.y;
            hv.z = hp.z + ga.z * (a.z - mean) * inv + gb.z;
            hv.w = hp.w + ga.w * (a.w - mean) * inv + gb.w;
        }
        hr4[c] = hv;
        float4 wk = wk4[c], wv = wv4[c], kl, vv;
        kl.x = hv.x * wk.x * LOG2E; kl.y = hv.y * wk.y * LOG2E;
        kl.z = hv.z * wk.z * LOG2E; kl.w = hv.w * wk.w * LOG2E;
        vv.x = hv.x * wv.x; vv.y = hv.y * wv.y;
        vv.z = hv.z * wv.z; vv.w = hv.w * wv.w;
        kr4[c] = kl;
        vr4[c] = vv;
        kmx = fmaxf(kmx, fmaxf(fmaxf(kl.x, kl.y), fmaxf(kl.z, kl.w)));
        kmn = fminf(kmn, fminf(fminf(kl.x, kl.y), fminf(kl.z, kl.w)));
    }
    for (int o = 1; o < 64; o <<= 1) {
        kmx = fmaxf(kmx, __shfl_xor(kmx, o));
        kmn = fminf(kmn, __shfl_xor(kmn, o));
    }
    __syncthreads();   // phase-A red reads done; LDS tables visible
    if ((tid & 63) == 0) { red[tid >> 6] = kmx; red[4 + (tid >> 6)] = kmn; }
    __syncthreads();
    kmx = fmaxf(fmaxf(red[0], red[1]), fmaxf(red[2], red[3]));
    kmn = fminf(fminf(red[4], red[5]), fminf(red[6], red[7]));

    // persist combined h row (one block per b)
    if (!FIRST && hcur != nullptr && h == 0 && ic == 0) {
        float4* hc4 = reinterpret_cast<float4*>(hcur + (size_t)b * G);
        for (int c = tid; c < C4; c += 256) hc4[c] = hr4[c];
    }

    // ---- phase C: softmax-weighted sums over j ----
    const int ig = tid >> 3, sl = tid & 7;
    const int i0 = ic * IPB + ig * ITR;      // even
    const bool valid = i0 < G;               // G even
    const int is = valid ? i0 : 0;

    const float2 hq = hr2[is >> 1];
    const float2 wq = *reinterpret_cast<const float2*>(WQ + (size_t)h * G + is);
    float q[ITR] = {hq.x * wq.x, hq.y * wq.y};
    float m[ITR], S1[ITR], S2[ITR];
#pragma unroll
    for (int r = 0; r < ITR; ++r) {
        m[r]  = fmaxf(q[r] * kmx, q[r] * kmn);
        S1[r] = 0.f;
        S2[r] = 0.f;
    }

#pragma unroll 2
    for (int c = sl; c < C4; c += JSL) {
        float4 kk = kr4[c];
        float4 vq = vr4[c];
#pragma unroll
        for (int r = 0; r < ITR; ++r) {
            float qq = q[r], mm = m[r];
            float e0 = __builtin_amdgcn_exp2f(fmaf(qq, kk.x, -mm));
            float e1 = __builtin_amdgcn_exp2f(fmaf(qq, kk.y, -mm));
            float e2 = __builtin_amdgcn_exp2f(fmaf(qq, kk.z, -mm));
            float e3 = __builtin_amdgcn_exp2f(fmaf(qq, kk.w, -mm));
            S1[r] += (e0 + e1) + (e2 + e3);
            S2[r] += (e0 * vq.x + e1 * vq.y) + (e2 * vq.z + e3 * vq.w);
        }
    }

#pragma unroll
    for (int r = 0; r < ITR; ++r) {
        S1[r] += __shfl_xor(S1[r], 1);
        S1[r] += __shfl_xor(S1[r], 2);
        S1[r] += __shfl_xor(S1[r], 4);
        S2[r] += __shfl_xor(S2[r], 1);
        S2[r] += __shfl_xor(S2[r], 2);
        S2[r] += __shfl_xor(S2[r], 4);
    }

    if (sl == 0 && valid) {
        const float w0h = W0[h];
        const float2 kt2 = kr2[i0 >> 1];
        const float2 vt2 = vr2[i0 >> 1];
        const float kli[ITR] = {kt2.x, kt2.y};
        const float vvi[ITR] = {vt2.x, vt2.y};
        float o[ITR];
#pragma unroll
        for (int r = 0; r < ITR; ++r) {
            float eii = __builtin_amdgcn_exp2f(fmaf(q[r], kli[r], -m[r]));
            o[r] = w0h * (S2[r] - eii * vvi[r]) / S1[r];
        }
        *reinterpret_cast<float2*>(ph + ((size_t)b * NH + h) * GP + i0) =
            make_float2(o[0], o[1]);
    }
}

// ---------------------------------------------------------------------------
// One logit per block: recombine layer-3 heads + LN on the fly, dot with
// fc row c.  grid (NC, NB) = 544 blocks (latency fully parallelized).
// ---------------------------------------------------------------------------
__global__ __launch_bounds__(256) void logits_kernel(
    const float* __restrict__ hprev, const float* __restrict__ php,
    const float* __restrict__ lna, const float* __restrict__ lnb,
    const float* __restrict__ fcw, const float* __restrict__ fcb,
    float* __restrict__ lgt)
{
    __shared__ __align__(16) float arow[G];
    __shared__ float red[8];
    const int c = blockIdx.x, b = blockIdx.y, tid = threadIdx.x;

    const float4* p0 = reinterpret_cast<const float4*>(php + ((size_t)b * NH + 0) * GP);
    const float4* p1 = reinterpret_cast<const float4*>(php + ((size_t)b * NH + 1) * GP);
    const float4* p2 = reinterpret_cast<const float4*>(php + ((size_t)b * NH + 2) * GP);
    const float4* p3 = reinterpret_cast<const float4*>(php + ((size_t)b * NH + 3) * GP);
    const float4* p4 = reinterpret_cast<const float4*>(php + ((size_t)b * NH + 4) * GP);
    float4* ar4 = reinterpret_cast<float4*>(arow);

    float s = 0.f, ss = 0.f;
    for (int k = tid; k < C4; k += 256) {
        float4 a = p0[k], t;
        t = p1[k]; a.x += t.x; a.y += t.y; a.z += t.z; a.w += t.w;
        t = p2[k]; a.x += t.x; a.y += t.y; a.z += t.z; a.w += t.w;
        t = p3[k]; a.x += t.x; a.y += t.y; a.z += t.z; a.w += t.w;
        t = p4[k]; a.x += t.x; a.y += t.y; a.z += t.z; a.w += t.w;
        ar4[k] = a;
        s  += (a.x + a.y) + (a.z + a.w);
        ss += (a.x * a.x + a.y * a.y) + (a.z * a.z + a.w * a.w);
    }
    for (int o = 1; o < 64; o <<= 1) {
        s  += __shfl_xor(s, o);
        ss += __shfl_xor(ss, o);
    }
    if ((tid & 63) == 0) { red[tid >> 6] = s; red[4 + (tid >> 6)] = ss; }
    __syncthreads();
    float S  = (red[0] + red[1]) + (red[2] + red[3]);
    float SS = (red[4] + red[5]) + (red[6] + red[7]);
    const float mean = S / (float)G;
    const float var  = fmaxf((SS - S * mean) / (float)(G - 1), 0.f);
    const float inv  = 1.f / (sqrtf(var) + LN_EPS);

    const float4* hp4 = reinterpret_cast<const float4*>(hprev + (size_t)b * G);
    const float4* ga4 = reinterpret_cast<const float4*>(lna);
    const float4* gb4 = reinterpret_cast<const float4*>(lnb);
    const float4* w4  = reinterpret_cast<const float4*>(fcw + (size_t)c * G);
    float acc = 0.f;
    for (int k = tid; k < C4; k += 256) {
        float4 a = ar4[k], hp = hp4[k], ga = ga4[k], gb = gb4[k], w = w4[k];
        float hx = hp.x + ga.x * (a.x - mean) * inv + gb.x;
        float hy = hp.y + ga.y * (a.y - mean) * inv + gb.y;
        float hz = hp.z + ga.z * (a.z - mean) * inv + gb.z;
        float hw = hp.w + ga.w * (a.w - mean) * inv + gb.w;
        acc += (hx * w.x + hy * w.y) + (hz * w.z + hw * w.w);
    }
    for (int o = 1; o < 64; o <<= 1) acc += __shfl_xor(acc, o);
    __syncthreads();
    if ((tid & 63) == 0) red[tid >> 6] = acc;
    __syncthreads();
    if (tid == 0)
        lgt[(size_t)b * NC + c] =
            (red[0] + red[1]) + (red[2] + red[3]) + fcb[c];
}

// out = log_softmax(logits) — one wave per batch row
__global__ __launch_bounds__(64) void lsm_kernel(
    const float* __restrict__ lgt, float* __restrict__ out)
{
    const int b = blockIdx.x, tid = threadIdx.x;
    float l = (tid < NC) ? lgt[(size_t)b * NC + tid] : -INFINITY;
    float mm = l;
    for (int o = 32; o; o >>= 1) mm = fmaxf(mm, __shfl_xor(mm, o));
    float e = (tid < NC) ? expf(l - mm) : 0.f;
    float se = e;
    for (int o = 32; o; o >>= 1) se += __shfl_xor(se, o);
    if (tid < NC) out[(size_t)b * NC + tid] = l - mm - logf(se);
}

// ---------------------------------------------------------------------------
extern "C" void kernel_launch(void* const* d_in, const int* in_sizes, int n_in,
                              void* d_out, int out_size, void* d_ws, size_t ws_size,
                              hipStream_t stream)
{
    const float* x    = (const float*)d_in[0];
    const float* WQ1  = (const float*)d_in[1];
    const float* WK1  = (const float*)d_in[2];
    const float* WV1  = (const float*)d_in[3];
    const float* W01  = (const float*)d_in[4];
    const float* WQ2  = (const float*)d_in[5];
    const float* WK2  = (const float*)d_in[6];
    const float* WV2  = (const float*)d_in[7];
    const float* W02  = (const float*)d_in[8];
    const float* WQ3  = (const float*)d_in[9];
    const float* WK3  = (const float*)d_in[10];
    const float* WV3  = (const float*)d_in[11];
    const float* W03  = (const float*)d_in[12];
    const float* lna  = (const float*)d_in[13];
    const float* lnb  = (const float*)d_in[14];
    const float* fcw  = (const float*)d_in[15];
    const float* fcb  = (const float*)d_in[16];
    float* out = (float*)d_out;

    const size_t PHS = (size_t)NB * NH * GP;
    float* pha = (float*)d_ws;           // layer 1 / 3 per-head rows
    float* phb = pha + PHS;              // layer 2 per-head rows
    float* h1  = phb + PHS;              // [NB,G]
    float* h2  = h1 + (size_t)NB * G;    // (unused h3 slot kept for clarity)
    float* lgt = h2 + (size_t)NB * G;    // [NB,NC]

    const dim3 agrid(ICH, NH, NB);       // (27,5,16) = 2160 blocks

    attn_layer<true><<<agrid, 256, 0, stream>>>(
        x, nullptr, lna, lnb, WQ1, WK1, WV1, W01, pha, nullptr);
    attn_layer<false><<<agrid, 256, 0, stream>>>(
        x, pha, lna, lnb, WQ2, WK2, WV2, W02, phb, h1);
    attn_layer<false><<<agrid, 256, 0, stream>>>(
        h1, phb, lna, lnb, WQ3, WK3, WV3, W03, pha, h2);
    logits_kernel<<<dim3(NC, NB), 256, 0, stream>>>(
        h1, pha, lna, lnb, fcw, fcb, lgt);   // hprev for layer 3 LN = h2? no:
    // NOTE: layer-3 residual base is h2 (the persisted combined row of layer 3's
    // input). attn_layer<false> #3 wrote h2 = combined(h1, phb). logits must
    // use hprev = h2 and php = pha (layer-3 head outputs).
    logits_kernel<<<dim3(NC, NB), 256, 0, stream>>>(
        h2, pha, lna, lnb, fcw, fcb, lgt);
    lsm_kernel<<<NB, 64, 0, stream>>>(lgt, out);
}

// Round 11
// 206.006 us; speedup vs baseline: 4.6269x; 1.0169x over previous
//
#include <hip/hip_runtime.h>
#include <math.h>

#define G      1708
#define GP     1728         // padded per-head row stride
#define C4     427          // float4 chunks per row
#define NH     5
#define NB     16
#define NC     34
#define JSL    16           // j-slices per i-group
#define ITR    2            // i per thread
#define IPB    32           // i per block = (256/JSL)*ITR
#define ICH    54           // ceil(G/IPB)
#define LN_EPS 1e-6f
#define LOG2E  1.4426950408889634f

// ---------------------------------------------------------------------------
// Fused per-layer attention. Block = (i-chunk, head, batch). Each block:
//  (A) [layers 2/3] recombine prev layer's per-head rows -> a, row LN stats
//      (identical redundant compute per block; deterministic)
//  (B) h = hprev + ln(a)  (layer1: h = x); build k*log2e, v rows in LDS;
//      block kmin/kmax (rank-1 exact row max: m_i = max(q*kmax, q*kmin))
//  (C) j-loop from LDS -> S1,S2 -> per-head output ph.
// grid (54,5,16)=4320 blocks, 20.5 KB LDS -> 7 blocks/CU, ~2.4 rounds.
// ---------------------------------------------------------------------------
template <bool FIRST>
__global__ __launch_bounds__(256) void attn_layer(
    const float* __restrict__ hprev, const float* __restrict__ php,
    const float* __restrict__ lna, const float* __restrict__ lnb,
    const float* __restrict__ WQ, const float* __restrict__ WK,
    const float* __restrict__ WV, const float* __restrict__ W0,
    float* __restrict__ ph, float* __restrict__ hcur)
{
    __shared__ __align__(16) float hrow[G];   // a, then h
    __shared__ __align__(16) float krow[G];
    __shared__ __align__(16) float vrow[G];
    __shared__ float red[8];

    const int ic = blockIdx.x, h = blockIdx.y, b = blockIdx.z;
    const int tid = threadIdx.x;

    const float4* hp4 = reinterpret_cast<const float4*>(hprev + (size_t)b * G);
    float4* hr4 = reinterpret_cast<float4*>(hrow);
    float4* kr4 = reinterpret_cast<float4*>(krow);
    float4* vr4 = reinterpret_cast<float4*>(vrow);
    const float2* hr2 = reinterpret_cast<const float2*>(hrow);
    const float2* kr2 = reinterpret_cast<const float2*>(krow);
    const float2* vr2 = reinterpret_cast<const float2*>(vrow);

    float mean = 0.f, inv = 0.f;
    if constexpr (!FIRST) {
        // ---- phase A: combine heads, LN stats ----
        const float4* p0 = reinterpret_cast<const float4*>(php + ((size_t)b * NH + 0) * GP);
        const float4* p1 = reinterpret_cast<const float4*>(php + ((size_t)b * NH + 1) * GP);
        const float4* p2 = reinterpret_cast<const float4*>(php + ((size_t)b * NH + 2) * GP);
        const float4* p3 = reinterpret_cast<const float4*>(php + ((size_t)b * NH + 3) * GP);
        const float4* p4 = reinterpret_cast<const float4*>(php + ((size_t)b * NH + 4) * GP);
        float s = 0.f, ss = 0.f;
        for (int c = tid; c < C4; c += 256) {
            float4 a = p0[c], t;
            t = p1[c]; a.x += t.x; a.y += t.y; a.z += t.z; a.w += t.w;
            t = p2[c]; a.x += t.x; a.y += t.y; a.z += t.z; a.w += t.w;
            t = p3[c]; a.x += t.x; a.y += t.y; a.z += t.z; a.w += t.w;
            t = p4[c]; a.x += t.x; a.y += t.y; a.z += t.z; a.w += t.w;
            hr4[c] = a;
            s  += (a.x + a.y) + (a.z + a.w);
            ss += (a.x * a.x + a.y * a.y) + (a.z * a.z + a.w * a.w);
        }
        for (int o = 1; o < 64; o <<= 1) {
            s  += __shfl_xor(s, o);
            ss += __shfl_xor(ss, o);
        }
        if ((tid & 63) == 0) { red[tid >> 6] = s; red[4 + (tid >> 6)] = ss; }
        __syncthreads();
        float S  = (red[0] + red[1]) + (red[2] + red[3]);
        float SS = (red[4] + red[5]) + (red[6] + red[7]);
        mean = S / (float)G;
        float var = fmaxf((SS - S * mean) / (float)(G - 1), 0.f);
        inv = 1.f / (sqrtf(var) + LN_EPS);
    }

    // ---- phase B: h row, k/v tables, block kmin/kmax ----
    const float4* wk4 = reinterpret_cast<const float4*>(WK + (size_t)h * G);
    const float4* wv4 = reinterpret_cast<const float4*>(WV + (size_t)h * G);
    const float4* ga4 = reinterpret_cast<const float4*>(lna);
    const float4* gb4 = reinterpret_cast<const float4*>(lnb);
    float kmx = -INFINITY, kmn = INFINITY;
    for (int c = tid; c < C4; c += 256) {
        float4 hv;
        if constexpr (FIRST) {
            hv = hp4[c];
        } else {
            float4 a = hr4[c], hp = hp4[c], ga = ga4[c], gb = gb4[c];
            hv.x = hp.x + ga.x * (a.x - mean) * inv + gb.x;
            hv.y = hp.y + ga.y * (a.y - mean) * inv + gb.y;
            hv.z = hp.z + ga.z * (a.z - mean) * inv + gb.z;
            hv.w = hp.w + ga.w * (a.w - mean) * inv + gb.w;
        }
        hr4[c] = hv;
        float4 wk = wk4[c], wv = wv4[c], kl, vv;
        kl.x = hv.x * wk.x * LOG2E; kl.y = hv.y * wk.y * LOG2E;
        kl.z = hv.z * wk.z * LOG2E; kl.w = hv.w * wk.w * LOG2E;
        vv.x = hv.x * wv.x; vv.y = hv.y * wv.y;
        vv.z = hv.z * wv.z; vv.w = hv.w * wv.w;
        kr4[c] = kl;
        vr4[c] = vv;
        kmx = fmaxf(kmx, fmaxf(fmaxf(kl.x, kl.y), fmaxf(kl.z, kl.w)));
        kmn = fminf(kmn, fminf(fminf(kl.x, kl.y), fminf(kl.z, kl.w)));
    }
    for (int o = 1; o < 64; o <<= 1) {
        kmx = fmaxf(kmx, __shfl_xor(kmx, o));
        kmn = fminf(kmn, __shfl_xor(kmn, o));
    }
    __syncthreads();   // phase-A red reads done; LDS tables visible
    if ((tid & 63) == 0) { red[tid >> 6] = kmx; red[4 + (tid >> 6)] = kmn; }
    __syncthreads();
    kmx = fmaxf(fmaxf(red[0], red[1]), fmaxf(red[2], red[3]));
    kmn = fminf(fminf(red[4], red[5]), fminf(red[6], red[7]));

    // persist combined h row (one block per b)
    if (!FIRST && hcur != nullptr && h == 0 && ic == 0) {
        float4* hc4 = reinterpret_cast<float4*>(hcur + (size_t)b * G);
        for (int c = tid; c < C4; c += 256) hc4[c] = hr4[c];
    }

    // ---- phase C: softmax-weighted sums over j ----
    const int ig = tid >> 4, sl = tid & 15;
    const int i0 = ic * IPB + ig * ITR;      // even
    const bool valid = i0 < G;               // G even
    const int is = valid ? i0 : 0;

    const float2 hq = hr2[is >> 1];
    const float2 wq = *reinterpret_cast<const float2*>(WQ + (size_t)h * G + is);
    float q[ITR] = {hq.x * wq.x, hq.y * wq.y};
    float m[ITR], S1[ITR], S2[ITR];
#pragma unroll
    for (int r = 0; r < ITR; ++r) {
        m[r]  = fmaxf(q[r] * kmx, q[r] * kmn);
        S1[r] = 0.f;
        S2[r] = 0.f;
    }

#pragma unroll 2
    for (int c = sl; c < C4; c += JSL) {
        float4 kk = kr4[c];
        float4 vq = vr4[c];
#pragma unroll
        for (int r = 0; r < ITR; ++r) {
            float qq = q[r], mm = m[r];
            float e0 = __builtin_amdgcn_exp2f(fmaf(qq, kk.x, -mm));
            float e1 = __builtin_amdgcn_exp2f(fmaf(qq, kk.y, -mm));
            float e2 = __builtin_amdgcn_exp2f(fmaf(qq, kk.z, -mm));
            float e3 = __builtin_amdgcn_exp2f(fmaf(qq, kk.w, -mm));
            S1[r] += (e0 + e1) + (e2 + e3);
            S2[r] += (e0 * vq.x + e1 * vq.y) + (e2 * vq.z + e3 * vq.w);
        }
    }

#pragma unroll
    for (int r = 0; r < ITR; ++r) {
        S1[r] += __shfl_xor(S1[r], 1);
        S1[r] += __shfl_xor(S1[r], 2);
        S1[r] += __shfl_xor(S1[r], 4);
        S1[r] += __shfl_xor(S1[r], 8);
        S2[r] += __shfl_xor(S2[r], 1);
        S2[r] += __shfl_xor(S2[r], 2);
        S2[r] += __shfl_xor(S2[r], 4);
        S2[r] += __shfl_xor(S2[r], 8);
    }

    if (sl == 0 && valid) {
        const float w0h = W0[h];
        const float2 kt2 = kr2[i0 >> 1];
        const float2 vt2 = vr2[i0 >> 1];
        const float kli[ITR] = {kt2.x, kt2.y};
        const float vvi[ITR] = {vt2.x, vt2.y};
        float o[ITR];
#pragma unroll
        for (int r = 0; r < ITR; ++r) {
            float eii = __builtin_amdgcn_exp2f(fmaf(q[r], kli[r], -m[r]));
            o[r] = w0h * (S2[r] - eii * vvi[r]) / S1[r];
        }
        *reinterpret_cast<float2*>(ph + ((size_t)b * NH + h) * GP + i0) =
            make_float2(o[0], o[1]);
    }
}

// ---------------------------------------------------------------------------
// One logit per block: recombine layer-3 heads + LN on the fly, dot with
// fc row c.  grid (NC, NB) = 544 blocks.
// ---------------------------------------------------------------------------
__global__ __launch_bounds__(256) void logits_kernel(
    const float* __restrict__ hprev, const float* __restrict__ php,
    const float* __restrict__ lna, const float* __restrict__ lnb,
    const float* __restrict__ fcw, const float* __restrict__ fcb,
    float* __restrict__ lgt)
{
    __shared__ __align__(16) float arow[G];
    __shared__ float red[8];
    const int c = blockIdx.x, b = blockIdx.y, tid = threadIdx.x;

    const float4* p0 = reinterpret_cast<const float4*>(php + ((size_t)b * NH + 0) * GP);
    const float4* p1 = reinterpret_cast<const float4*>(php + ((size_t)b * NH + 1) * GP);
    const float4* p2 = reinterpret_cast<const float4*>(php + ((size_t)b * NH + 2) * GP);
    const float4* p3 = reinterpret_cast<const float4*>(php + ((size_t)b * NH + 3) * GP);
    const float4* p4 = reinterpret_cast<const float4*>(php + ((size_t)b * NH + 4) * GP);
    float4* ar4 = reinterpret_cast<float4*>(arow);

    float s = 0.f, ss = 0.f;
    for (int k = tid; k < C4; k += 256) {
        float4 a = p0[k], t;
        t = p1[k]; a.x += t.x; a.y += t.y; a.z += t.z; a.w += t.w;
        t = p2[k]; a.x += t.x; a.y += t.y; a.z += t.z; a.w += t.w;
        t = p3[k]; a.x += t.x; a.y += t.y; a.z += t.z; a.w += t.w;
        t = p4[k]; a.x += t.x; a.y += t.y; a.z += t.z; a.w += t.w;
        ar4[k] = a;
        s  += (a.x + a.y) + (a.z + a.w);
        ss += (a.x * a.x + a.y * a.y) + (a.z * a.z + a.w * a.w);
    }
    for (int o = 1; o < 64; o <<= 1) {
        s  += __shfl_xor(s, o);
        ss += __shfl_xor(ss, o);
    }
    if ((tid & 63) == 0) { red[tid >> 6] = s; red[4 + (tid >> 6)] = ss; }
    __syncthreads();
    float S  = (red[0] + red[1]) + (red[2] + red[3]);
    float SS = (red[4] + red[5]) + (red[6] + red[7]);
    const float mean = S / (float)G;
    const float var  = fmaxf((SS - S * mean) / (float)(G - 1), 0.f);
    const float inv  = 1.f / (sqrtf(var) + LN_EPS);

    const float4* hp4 = reinterpret_cast<const float4*>(hprev + (size_t)b * G);
    const float4* ga4 = reinterpret_cast<const float4*>(lna);
    const float4* gb4 = reinterpret_cast<const float4*>(lnb);
    const float4* w4  = reinterpret_cast<const float4*>(fcw + (size_t)c * G);
    float acc = 0.f;
    for (int k = tid; k < C4; k += 256) {
        float4 a = ar4[k], hp = hp4[k], ga = ga4[k], gb = gb4[k], w = w4[k];
        float hx = hp.x + ga.x * (a.x - mean) * inv + gb.x;
        float hy = hp.y + ga.y * (a.y - mean) * inv + gb.y;
        float hz = hp.z + ga.z * (a.z - mean) * inv + gb.z;
        float hw = hp.w + ga.w * (a.w - mean) * inv + gb.w;
        acc += (hx * w.x + hy * w.y) + (hz * w.z + hw * w.w);
    }
    for (int o = 1; o < 64; o <<= 1) acc += __shfl_xor(acc, o);
    __syncthreads();
    if ((tid & 63) == 0) red[tid >> 6] = acc;
    __syncthreads();
    if (tid == 0)
        lgt[(size_t)b * NC + c] =
            (red[0] + red[1]) + (red[2] + red[3]) + fcb[c];
}

// out = log_softmax(logits) — one wave per batch row
__global__ __launch_bounds__(64) void lsm_kernel(
    const float* __restrict__ lgt, float* __restrict__ out)
{
    const int b = blockIdx.x, tid = threadIdx.x;
    float l = (tid < NC) ? lgt[(size_t)b * NC + tid] : -INFINITY;
    float mm = l;
    for (int o = 32; o; o >>= 1) mm = fmaxf(mm, __shfl_xor(mm, o));
    float e = (tid < NC) ? expf(l - mm) : 0.f;
    float se = e;
    for (int o = 32; o; o >>= 1) se += __shfl_xor(se, o);
    if (tid < NC) out[(size_t)b * NC + tid] = l - mm - logf(se);
}

// ---------------------------------------------------------------------------
extern "C" void kernel_launch(void* const* d_in, const int* in_sizes, int n_in,
                              void* d_out, int out_size, void* d_ws, size_t ws_size,
                              hipStream_t stream)
{
    const float* x    = (const float*)d_in[0];
    const float* WQ1  = (const float*)d_in[1];
    const float* WK1  = (const float*)d_in[2];
    const float* WV1  = (const float*)d_in[3];
    const float* W01  = (const float*)d_in[4];
    const float* WQ2  = (const float*)d_in[5];
    const float* WK2  = (const float*)d_in[6];
    const float* WV2  = (const float*)d_in[7];
    const float* W02  = (const float*)d_in[8];
    const float* WQ3  = (const float*)d_in[9];
    const float* WK3  = (const float*)d_in[10];
    const float* WV3  = (const float*)d_in[11];
    const float* W03  = (const float*)d_in[12];
    const float* lna  = (const float*)d_in[13];
    const float* lnb  = (const float*)d_in[14];
    const float* fcw  = (const float*)d_in[15];
    const float* fcb  = (const float*)d_in[16];
    float* out = (float*)d_out;

    const size_t PHS = (size_t)NB * NH * GP;
    float* pha = (float*)d_ws;           // layer 1 / 3 per-head rows
    float* phb = pha + PHS;              // layer 2 per-head rows
    float* h1  = phb + PHS;              // [NB,G]  (combined input of layer 3)
    float* h2  = h1 + (size_t)NB * G;    // [NB,G]  (combined input of logits LN)
    float* lgt = h2 + (size_t)NB * G;    // [NB,NC]

    const dim3 agrid(ICH, NH, NB);       // (54,5,16) = 4320 blocks

    attn_layer<true><<<agrid, 256, 0, stream>>>(
        x, nullptr, lna, lnb, WQ1, WK1, WV1, W01, pha, nullptr);
    attn_layer<false><<<agrid, 256, 0, stream>>>(
        x, pha, lna, lnb, WQ2, WK2, WV2, W02, phb, h1);
    attn_layer<false><<<agrid, 256, 0, stream>>>(
        h1, phb, lna, lnb, WQ3, WK3, WV3, W03, pha, h2);
    // layer-3 residual base is h2 = combined(h1, phb); layer-3 heads in pha
    logits_kernel<<<dim3(NC, NB), 256, 0, stream>>>(
        h2, pha, lna, lnb, fcw, fcb, lgt);
    lsm_kernel<<<NB, 64, 0, stream>>>(lgt, out);
}